// Round 15
// baseline (581.045 us; speedup 1.0000x reference)
//
#include <hip/hip_runtime.h>

typedef unsigned short u16;
typedef unsigned char u8;
typedef __attribute__((ext_vector_type(4))) float f32x4;
typedef __attribute__((ext_vector_type(8))) short short8;
typedef __attribute__((ext_vector_type(8))) unsigned char uchar8;

#define N_G_   32768
#define E_G_   131072
#define E_LG_  262144
#define H_     128
#define B_     256
#define TASKS_ 10
#define KPAD_  288
#define LDST_  296   // LDS row stride (u16) for msg A tile
#define CPAD_  132   // padded f32 row stride for C epilogue tile
#define APAD_  136   // padded u16 row stride for fused agg->gemm A tile
#define SCAP_  256   // staged-src capacity per block
#define INVBN_ 0.9999950000374997f   // 1/sqrt(1+1e-5)
#define NCVT_  20
#define TOTAL_CANON_ 5352216

__device__ __forceinline__ float bf2f(u16 h){
  union { unsigned int u; float f; } v; v.u = ((unsigned int)h) << 16; return v.f;
}
__device__ __forceinline__ u16 f2bf(float f){
  union { float f; unsigned int u; } v; v.f = f;
  unsigned int u = v.u + 0x7fffu + ((v.u >> 16) & 1u);  // RNE
  return (u16)(u >> 16);
}
// e5m2 = top byte of fp16 (same exponent field), RNE
__device__ __forceinline__ u8 f2e5m2(float f){
  union { _Float16 h; u16 u; } v; v.h = (_Float16)f;
  u16 u = v.u + 0x7Fu + ((v.u >> 8) & 1u);
  return (u8)(u >> 8);
}
__device__ __forceinline__ float e5m22f(u8 b){
  union { u16 u; _Float16 h; } v; v.u = ((u16)b) << 8;
  return (float)v.h;
}

// ---- dtype detect
__global__ void k_detect(const unsigned int* __restrict__ x, int* __restrict__ flag){
  __shared__ int sm[256];
  unsigned int v = x[threadIdx.x];
  unsigned int e = (v >> 7) & 0xFFu;
  sm[threadIdx.x] = (e >= 110u && e <= 140u) ? 1 : 0;
  __syncthreads();
  for (int s=128;s>0;s>>=1){ if (threadIdx.x < s) sm[threadIdx.x] += sm[threadIdx.x+s]; __syncthreads(); }
  if (threadIdx.x == 0) flag[0] = (sm[0] > 128) ? 1 : 0;
}

struct CvtArgs { const void* src[NCVT_]; int start[NCVT_]; int count[NCVT_]; };

__global__ void k_cvt(CvtArgs a, int total, const int* __restrict__ flag, u16* __restrict__ dst){
  int i = blockIdx.x*256 + threadIdx.x;
  if (i >= total) return;
  int s = 0;
  #pragma unroll
  for (int j=1;j<NCVT_;j++) if (i >= a.start[j]) s = j;
  int off = i - a.start[s];
  if (off >= a.count[s]) { dst[i] = 0; return; }
  if (flag[0]) dst[i] = ((const u16*)a.src[s])[off];
  else         dst[i] = f2bf(((const float*)a.src[s])[off]);
}

// ---- pack W_gcn [l][k][n] -> WTg [l][n][k]; W_msg [k][n] -> WTm [n][288]
__global__ void k_pack(const u16* __restrict__ Wg, const u16* __restrict__ Wm,
                       u16* __restrict__ WTg, u16* __restrict__ WTm){
  int idx = blockIdx.x*256 + threadIdx.x;
  if (idx < 4*128*128){
    int l = idx >> 14, n = (idx >> 7) & 127, k = idx & 127;
    WTg[idx] = Wg[((l<<7) + k)*128 + n];
  }
  if (idx < 128*KPAD_){
    int n = idx / KPAD_, kp = idx % KPAD_;
    WTm[idx] = (kp < 276) ? Wm[kp*128 + n] : (u16)0;
  }
}

// ---- encoder
__global__ __launch_bounds__(256) void k_enc(const u16* __restrict__ xg, const u16* __restrict__ We,
                      const u16* __restrict__ be, u16* __restrict__ hn){
  int idx = blockIdx.x*256 + threadIdx.x;
  int r = idx >> 7, c = idx & 127;
  float acc = bf2f(be[c]);
  const u16* xr = xg + r*32;
  #pragma unroll
  for (int k=0;k<32;k++) acc += bf2f(xr[k]) * bf2f(We[k*128 + c]);
  hn[idx] = f2bf(acc);
}

// ---- msg GEMM with coalesced LDS epilogue (reuses As after barrier)
__global__ __launch_bounds__(256) void k_msg(const u16* __restrict__ hn, const u16* __restrict__ eag,
     const u16* __restrict__ xlg, const int* __restrict__ eig,
     const u16* __restrict__ WTm, const u16* __restrict__ bmsg, u16* __restrict__ h){
  __shared__ __align__(16) u16 As[64*LDST_];
  int tid = threadIdx.x;
  int e0 = blockIdx.x * 64;
  {
    int i = tid >> 2;
    int j = tid & 3;
    int e = e0 + i;
    int s = eig[e];
    int d = eig[E_G_ + e];
    u16* rowp = As + i*LDST_;
    const u16* ps = hn + s*128 + j*32;
    const u16* pd = hn + d*128 + j*32;
    #pragma unroll
    for (int q=0;q<4;q++) *(short8*)(rowp + j*32 + q*8)       = *(const short8*)(ps + q*8);
    #pragma unroll
    for (int q=0;q<4;q++) *(short8*)(rowp + 128 + j*32 + q*8) = *(const short8*)(pd + q*8);
    if (j == 0){
      *(short8*)(rowp + 256) = *(const short8*)(eag + e*16);
      *(short8*)(rowp + 264) = *(const short8*)(eag + e*16 + 8);
      *(ushort4*)(rowp + 272) = *(const ushort4*)(xlg + e*4);
      *(ushort4*)(rowp + 276) = (ushort4){0,0,0,0};
      *(short8*)(rowp + 280) = (short8){0,0,0,0,0,0,0,0};
    }
  }
  __syncthreads();
  int wave = tid >> 6, lane = tid & 63, quad = lane >> 4, l16 = lane & 15;
  int arow = wave*16 + l16;
  f32x4 acc[8];
  #pragma unroll
  for (int ct=0;ct<8;ct++) acc[ct] = (f32x4){0.f,0.f,0.f,0.f};
  for (int ks=0; ks<KPAD_; ks+=32){
    short8 af = *(const short8*)(As + arow*LDST_ + ks + quad*8);
    #pragma unroll
    for (int ct=0;ct<8;ct++){
      short8 bfr = *(const short8*)(WTm + (ct*16 + l16)*KPAD_ + ks + quad*8);
      acc[ct] = __builtin_amdgcn_mfma_f32_16x16x32_bf16(af, bfr, acc[ct], 0,0,0);
    }
  }
  __syncthreads();
  float* Cs = (float*)As;
  {
    int lrow = wave*16 + quad*4;
    #pragma unroll
    for (int ct=0;ct<8;ct++){
      int col = ct*16 + l16;
      #pragma unroll
      for (int i=0;i<4;i++) Cs[(lrow+i)*CPAD_ + col] = acc[ct][i];
    }
  }
  __syncthreads();
  #pragma unroll
  for (int p=0;p<4;p++){
    int s = p*256 + tid;
    int lrow = s >> 4, c0 = (s & 15) * 8;
    const float* cp = Cs + lrow*CPAD_ + c0;
    short8 bs = *(const short8*)(bmsg + c0);
    short8 ov;
    #pragma unroll
    for (int k=0;k<8;k++) ov[k] = (short)f2bf(cp[k] + bf2f((u16)bs[k]));
    *(short8*)(h + (size_t)(e0 + lrow)*128 + c0) = ov;
  }
}

// ---- FUSED: softmax-agg (16 dsts, staged srcs, prefetched, fp8 w) -> LDS -> MFMA -> epilogue
__global__ __launch_bounds__(256) void k_agg_gemm(
    const u16* __restrict__ gin,      // gather input (pre-transformed for l>0)
    const u16* __restrict__ hres,     // residual input (raw)
    const int* __restrict__ srcs, const int* __restrict__ off,
    const u8* __restrict__ w, const u16* __restrict__ tvals, int layer,
    const u16* __restrict__ WT, const u16* __restrict__ bg,
    const u16* __restrict__ gamma, const u16* __restrict__ beta,
    u16* __restrict__ hout, u16* __restrict__ h2out, int residual, int write_h2){
  __shared__ __align__(16) float Cs[16*CPAD_];      // 8448 B; aliased as u16 As (stride APAD_)
  __shared__ int srcs_s[SCAP_];
  u16* As = (u16*)Cs;
  int tid = threadIdx.x;
  int e0 = blockIdx.x*16;

  // ---- stage block's src list (breaks the dependent-load chain)
  int kbB = off[e0], keB = off[e0+16];
  int cnt = keB - kbB;
  for (int i = tid; i < cnt && i < SCAP_; i += 256) srcs_s[i] = srcs[kbB + i];
  __syncthreads();

  // ---- phase A: per-dst serial softmax-agg with k+1 prefetch
  {
    int r = tid >> 4;
    int c0 = (tid & 15) * 8;
    int g = e0 + r;
    float t = bf2f(tvals[layer]);
    float den[8]={0.f,0.f,0.f,0.f,0.f,0.f,0.f,0.f};
    float num[8]={0.f,0.f,0.f,0.f,0.f,0.f,0.f,0.f};
    int kb = off[g], ke = off[g+1];
    short8 xu; uchar8 wu;
    if (kb < ke){
      int i0 = kb - kbB;
      int s0 = (i0 < SCAP_) ? srcs_s[i0] : srcs[kb];
      xu = *(const short8*)(gin + (size_t)s0*128 + c0);
      wu = *(const uchar8*)(w + (size_t)kb*128 + c0);
    }
    for (int k = kb; k < ke; k++){
      short8 xn; uchar8 wn;
      if (k+1 < ke){
        int i1 = k+1 - kbB;
        int s1 = (i1 < SCAP_) ? srcs_s[i1] : srcs[k+1];
        xn = *(const short8*)(gin + (size_t)s1*128 + c0);
        wn = *(const uchar8*)(w + (size_t)(k+1)*128 + c0);
      }
      #pragma unroll
      for (int j=0;j<8;j++){
        float m  = fmaxf(bf2f((u16)xu[j])*e5m22f((u8)wu[j]), 0.f);
        float e1 = __expf(m*t);
        den[j] += e1;
        num[j] = fmaf(e1, m, num[j]);
      }
      xu = xn; wu = wn;
    }
    short8 xdu = *(const short8*)(gin + (size_t)g*128 + c0);
    short8 ov;
    #pragma unroll
    for (int j=0;j<8;j++)
      ov[j] = (short)f2bf(bf2f((u16)xdu[j]) + (den[j] > 0.f ? num[j]/den[j] : 0.f));
    *(short8*)(As + r*APAD_ + c0) = ov;
  }
  __syncthreads();

  // ---- phase B: 4 waves; wave handles 2 col-tiles of the 16x128 output
  int wave = tid >> 6, lane = tid & 63, quad = lane >> 4, l16 = lane & 15;
  f32x4 acc[2];
  acc[0] = (f32x4){0.f,0.f,0.f,0.f};
  acc[1] = (f32x4){0.f,0.f,0.f,0.f};
  #pragma unroll
  for (int ks=0;ks<128;ks+=32){
    short8 af = *(const short8*)(As + l16*APAD_ + ks + quad*8);
    #pragma unroll
    for (int c2=0;c2<2;c2++){
      int ct = wave*2 + c2;
      short8 bfr = *(const short8*)(WT + (ct*16 + l16)*128 + ks + quad*8);
      acc[c2] = __builtin_amdgcn_mfma_f32_16x16x32_bf16(af, bfr, acc[c2], 0,0,0);
    }
  }
  __syncthreads();      // done reading As; Cs aliases it
  {
    int lrow = quad*4;
    #pragma unroll
    for (int c2=0;c2<2;c2++){
      int col = (wave*2 + c2)*16 + l16;
      #pragma unroll
      for (int i=0;i<4;i++) Cs[(lrow+i)*CPAD_ + col] = acc[c2][i];
    }
  }
  __syncthreads();

  // ---- epilogue: hout = C + b (+ res); h2out = relu(bn(hout)) if requested
  {
    int lrow = tid >> 4, ce = (tid & 15) * 8;
    const float* cp = Cs + lrow*CPAD_ + ce;
    size_t goff = (size_t)(e0 + lrow)*128 + ce;
    short8 bs = *(const short8*)(bg + ce);
    float v[8];
    #pragma unroll
    for (int k=0;k<8;k++) v[k] = cp[k] + bf2f((u16)bs[k]);
    if (residual){
      short8 hs = *(const short8*)(hres + goff);
      #pragma unroll
      for (int k=0;k<8;k++) v[k] += bf2f((u16)hs[k]);
    }
    short8 ov;
    #pragma unroll
    for (int k=0;k<8;k++) ov[k] = (short)f2bf(v[k]);
    *(short8*)(hout + goff) = ov;
    if (write_h2){
      short8 gs = *(const short8*)(gamma + layer*128 + ce);
      short8 es = *(const short8*)(beta  + layer*128 + ce);
      short8 o2;
      #pragma unroll
      for (int k=0;k<8;k++)
        o2[k] = (short)f2bf(fmaxf(fmaf(v[k], bf2f((u16)gs[k])*INVBN_, bf2f((u16)es[k])), 0.f));
      *(short8*)(h2out + goff) = o2;
    }
  }
}

// ---- merged CSR build: counts for both graphs in one dispatch
__global__ void k_count_both(const int* __restrict__ eilg_dst, const int* __restrict__ eig_dst,
                             int* __restrict__ cnt1, int* __restrict__ cnt2){
  int i = blockIdx.x*256 + threadIdx.x;
  if (i < E_LG_) atomicAdd(&cnt1[eilg_dst[i]], 1);
  else {
    int j = i - E_LG_;
    if (j < E_G_) atomicAdd(&cnt2[eig_dst[j]], 1);
  }
}
__global__ void k_bsum_both(const int* __restrict__ cnt1, const int* __restrict__ cnt2,
                            int* __restrict__ bsum){
  __shared__ int sm[256];
  int b = blockIdx.x;
  int v;
  if (b < 512) v = cnt1[b*256 + threadIdx.x];
  else         v = cnt2[(b-512)*256 + threadIdx.x];
  sm[threadIdx.x] = v;
  __syncthreads();
  for (int s=128;s>0;s>>=1){ if (threadIdx.x < s) sm[threadIdx.x] += sm[threadIdx.x+s]; __syncthreads(); }
  if (threadIdx.x==0) bsum[b] = sm[0];
}
__global__ void k_scanb_both(const int* __restrict__ bsum, int* __restrict__ bbase,
                             int* __restrict__ off1, int* __restrict__ off2){
  __shared__ int sm[1024];
  int t = threadIdx.x;
  {
    int v = (t < 512) ? bsum[t] : 0;
    sm[t] = v; __syncthreads();
    for (int d=1; d<1024; d<<=1){
      int u = (t>=d) ? sm[t-d] : 0;
      __syncthreads();
      sm[t] += u;
      __syncthreads();
    }
    if (t < 512) bbase[t] = sm[t] - v;
    if (t == 511) off1[E_G_] = sm[511];
  }
  __syncthreads();
  {
    int v = (t < 128) ? bsum[512 + t] : 0;
    sm[t] = v; __syncthreads();
    for (int d=1; d<1024; d<<=1){
      int u = (t>=d) ? sm[t-d] : 0;
      __syncthreads();
      sm[t] += u;
      __syncthreads();
    }
    if (t < 128) bbase[512 + t] = sm[t] - v;
    if (t == 127) off2[N_G_] = sm[127];
  }
}
// 640 blocks; also zeroes cnt in place (becomes scatter cursor)
__global__ void k_offsets_both(int* __restrict__ cnt1, int* __restrict__ cnt2,
                               const int* __restrict__ bbase,
                               int* __restrict__ off1, int* __restrict__ off2){
  __shared__ int sm[256];
  int b = blockIdx.x;
  int t = threadIdx.x;
  int* cnt; int* off; int i;
  if (b < 512){ cnt = cnt1; off = off1; i = b*256 + t; }
  else        { cnt = cnt2; off = off2; i = (b-512)*256 + t; }
  int v = cnt[i];
  cnt[i] = 0;
  sm[t] = v; __syncthreads();
  for (int d=1; d<256; d<<=1){
    int u = (t>=d) ? sm[t-d] : 0;
    __syncthreads();
    sm[t] += u;
    __syncthreads();
  }
  off[i] = bbase[b] + sm[t] - v;
}
__global__ void k_scatter_both(const int* __restrict__ eilg, const int* __restrict__ eig,
                               const int* __restrict__ off1, int* __restrict__ cnt1,
                               const int* __restrict__ off2, int* __restrict__ cnt2,
                               int* __restrict__ srcs, int* __restrict__ eidp,
                               int* __restrict__ eids){
  int i = blockIdx.x*256 + threadIdx.x;
  if (i < E_LG_){
    int s = eilg[i], d = eilg[E_LG_ + i];
    int p = off1[d] + atomicAdd(&cnt1[d], 1);
    srcs[p] = s;
    eidp[p] = i;
  } else {
    int e = i - E_LG_;
    if (e < E_G_){
      int d = eig[E_G_ + e];
      int p = off2[d] + atomicAdd(&cnt2[d], 1);
      eids[p] = e;
    }
  }
}

// ---- precompute w_sorted as fp8 e5m2 (grid-stride persistent, 16 lanes x 8 ch)
__global__ __launch_bounds__(256) void k_wprep(const int* __restrict__ srcs, const int* __restrict__ eidp,
    const u16* __restrict__ dbas, const u16* __restrict__ ealg,
    const u16* __restrict__ Wnb, const u16* __restrict__ bnb,
    const u16* __restrict__ Web, const u16* __restrict__ beb,
    u8* __restrict__ w){
  int c0 = (threadIdx.x & 15) * 8;
  float wnb[4][8], web[4][8], vbn[8], vbe[8];
  #pragma unroll
  for (int i=0;i<4;i++){
    short8 a = *(const short8*)(Wnb + i*128 + c0);
    short8 b = *(const short8*)(Web + i*128 + c0);
    #pragma unroll
    for (int j=0;j<8;j++){ wnb[i][j]=bf2f((u16)a[j]); web[i][j]=bf2f((u16)b[j]); }
  }
  {
    short8 a = *(const short8*)(bnb + c0);
    short8 b = *(const short8*)(beb + c0);
    #pragma unroll
    for (int j=0;j<8;j++){ vbn[j]=bf2f((u16)a[j]); vbe[j]=bf2f((u16)b[j]); }
  }
  int g0 = blockIdx.x*16 + (threadIdx.x >> 4);
  int gs = gridDim.x*16;
  for (int p = g0; p < E_LG_; p += gs){
    int sidx = srcs[p];
    int eidx = eidp[p];
    ushort4 du = *(const ushort4*)(dbas + sidx*4);
    ushort4 eu = *(const ushort4*)(ealg + eidx*4);
    float db[4] = {bf2f(du.x), bf2f(du.y), bf2f(du.z), bf2f(du.w)};
    float ev[4] = {bf2f(eu.x), bf2f(eu.y), bf2f(eu.z), bf2f(eu.w)};
    uchar8 ov;
    #pragma unroll
    for (int j=0;j<8;j++){
      float nbv = vbn[j] + db[0]*wnb[0][j] + db[1]*wnb[1][j] + db[2]*wnb[2][j] + db[3]*wnb[3][j];
      float ebv = vbe[j] + ev[0]*web[0][j] + ev[1]*web[1][j] + ev[2]*web[2][j] + ev[3]*web[3][j];
      ov[j] = f2e5m2(nbv * ebv);
    }
    *(uchar8*)(w + (size_t)p*128 + c0) = ov;
  }
}

// ---- stage 1 pooling: final bn + per-node edge-sum -> node_emb
__global__ __launch_bounds__(256) void k_pool_nodes(const u16* __restrict__ h, const int* __restrict__ off2,
    const int* __restrict__ eids,
    const u16* __restrict__ gamma, const u16* __restrict__ beta,
    float* __restrict__ node_emb){
  int tid = blockIdx.x*256 + threadIdx.x;
  int n = tid >> 5;
  int c0 = (tid & 31)*4;
  ushort4 ga = *(const ushort4*)(gamma + 3*128 + c0);
  ushort4 be = *(const ushort4*)(beta + 3*128 + c0);
  float gg[4] = {bf2f(ga.x)*INVBN_, bf2f(ga.y)*INVBN_, bf2f(ga.z)*INVBN_, bf2f(ga.w)*INVBN_};
  float bt[4] = {bf2f(be.x), bf2f(be.y), bf2f(be.z), bf2f(be.w)};
  float s[4] = {0.f,0.f,0.f,0.f};
  int kb = off2[n], ke = off2[n+1];
  for (int k=kb; k<ke; k++){
    int e = eids[k];
    ushort4 xu = *(const ushort4*)(h + (size_t)e*128 + c0);
    float xs[4] = {bf2f(xu.x), bf2f(xu.y), bf2f(xu.z), bf2f(xu.w)};
    #pragma unroll
    for (int j=0;j<4;j++) s[j] += fmaf(xs[j], gg[j], bt[j]);
  }
  f32x4 ov = {s[0], s[1], s[2], s[3]};
  *(f32x4*)(node_emb + (size_t)n*128 + c0) = ov;
}

// ---- stage 2: per-batch mean + fused prediction GEMV
__global__ __launch_bounds__(128) void k_poolpred(const float* __restrict__ node_emb,
    const int* __restrict__ bidx,
    const u16* __restrict__ Wp, const u16* __restrict__ bp,
    const int* __restrict__ flag, void* __restrict__ out){
  int b = blockIdx.x;
  int t = threadIdx.x;
  int lo = 0, hi_s = N_G_;
  { int l = 0, r = N_G_;
    while (l < r){ int m = (l+r)>>1; if (bidx[m] < b) l = m+1; else r = m; }
    lo = l;
    l = lo; r = N_G_;
    while (l < r){ int m = (l+r)>>1; if (bidx[m] < b+1) l = m+1; else r = m; }
    hi_s = l;
  }
  float s = 0.f;
  for (int n=lo; n<hi_s; n++) s += node_emb[(size_t)n*128 + t];
  __shared__ float sm[128];
  sm[t] = s;
  __syncthreads();
  if (t < TASKS_){
    float inv = 1.0f / fmaxf((float)(hi_s - lo), 1.0f);
    float acc = bf2f(bp[t]);
    #pragma unroll 4
    for (int c=0;c<128;c++) acc += sm[c]*inv * bf2f(Wp[c*TASKS_ + t]);
    if (flag[0]) ((u16*)out)[b*TASKS_ + t] = f2bf(acc);
    else         ((float*)out)[b*TASKS_ + t] = acc;
  }
}

extern "C" void kernel_launch(void* const* d_in, const int* in_sizes, int n_in,
                              void* d_out, int out_size, void* d_ws, size_t ws_size,
                              hipStream_t stream){
  const int* eig  = (const int*)d_in[5];
  const int* eilg = (const int*)d_in[6];
  const int* bidx = (const int*)d_in[7];

  char* ws = (char*)d_ws; size_t o = 0;
  auto carve = [&](size_t b)->char*{ char* p = ws + o; o += (b + 255) & ~(size_t)255; return p; };
  int*  flag  = (int*) carve(256);
  u16*  canon = (u16*) carve((size_t)TOTAL_CANON_*2);
  u16*  hr0   = (u16*) carve((size_t)E_G_*H_*2);   // raw ping
  u16*  hr1   = (u16*) carve((size_t)E_G_*H_*2);   // raw pong
  u16*  ht0   = (u16*) carve((size_t)E_G_*H_*2);   // transformed ping
  u16*  ht1   = (u16*) carve((size_t)E_G_*H_*2);   // transformed pong
  u16*  hn    = (u16*) carve((size_t)N_G_*H_*2);
  u16*  WTg   = (u16*) carve((size_t)4*128*128*2);
  u16*  WTm   = (u16*) carve((size_t)128*KPAD_*2);
  int*  cntB  = (int*) carve((size_t)(E_G_+N_G_)*4);   // cnt1 | cnt2 contiguous
  int*  cnt1  = cntB;
  int*  cnt2  = cntB + E_G_;
  int*  off1  = (int*) carve((size_t)(E_G_+1)*4);
  int*  off2  = (int*) carve((size_t)(N_G_+1)*4);
  int*  srcs  = (int*) carve((size_t)E_LG_*4);
  int*  eidp  = (int*) carve((size_t)E_LG_*4);
  int*  eids  = (int*) carve((size_t)E_G_*4);
  int*  bsum  = (int*) carve(1024*4);
  int*  bbase = (int*) carve(1024*4);
  float* node_emb = (float*)carve((size_t)N_G_*H_*4);
  u8*   w_sorted = (u8*)carve((size_t)E_LG_*H_);
  (void)in_sizes; (void)n_in; (void)out_size; (void)ws_size;

  static const int di[NCVT_] = {0,1,2,3,4, 8,9,10,11,12,13,14,15,16,17,18,19,20,21,22};
  static const int st[NCVT_] = {0,1048576,3145728,3670016,4194304,
                                5242880,5246976,5247104,5282432,5282560,
                                5283072,5283200,5283712,5283840,5349376,
                                5349888,5349896,5350408,5350920,5352200};
  static const int cn[NCVT_] = {1048576,2097152,524288,524288,1048576,
                                4096,128,35328,128,512,
                                128,512,128,65536,512,
                                4,512,512,1280,10};
  CvtArgs ca;
  for (int i=0;i<NCVT_;i++){ ca.src[i]=d_in[di[i]]; ca.start[i]=st[i]; ca.count[i]=cn[i]; }

  const u16* x_g   = canon + st[0];
  const u16* ea_g  = canon + st[1];
  const u16* x_lg  = canon + st[2];
  const u16* dbas  = canon + st[3];
  const u16* ea_lg = canon + st[4];
  const u16* W_enc = canon + st[5];
  const u16* b_enc = canon + st[6];
  const u16* W_msg = canon + st[7];
  const u16* b_msg = canon + st[8];
  const u16* W_nb  = canon + st[9];
  const u16* b_nb  = canon + st[10];
  const u16* W_eb  = canon + st[11];
  const u16* b_eb  = canon + st[12];
  const u16* W_gcn = canon + st[13];
  const u16* b_gcn = canon + st[14];
  const u16* t_vals= canon + st[15];
  const u16* gamma = canon + st[16];
  const u16* beta  = canon + st[17];
  const u16* W_pred= canon + st[18];
  const u16* b_pred= canon + st[19];

  k_detect<<<1,256,0,stream>>>((const unsigned int*)d_in[0], flag);
  k_cvt<<<(TOTAL_CANON_+255)/256,256,0,stream>>>(ca, TOTAL_CANON_, flag, canon);

  k_pack<<<256,256,0,stream>>>(W_gcn, W_msg, WTg, WTm);
  k_enc<<<N_G_*H_/256,256,0,stream>>>(x_g, W_enc, b_enc, hn);
  k_msg<<<E_G_/64,256,0,stream>>>(hn, ea_g, x_lg, eig, WTm, b_msg, hr0);

  // merged CSR build (line-graph dst + graph dst)
  hipMemsetAsync(cntB, 0, (size_t)(E_G_+N_G_)*4, stream);
  k_count_both<<<(E_LG_+E_G_)/256,256,0,stream>>>(eilg + E_LG_, eig + E_G_, cnt1, cnt2);
  k_bsum_both<<<640,256,0,stream>>>(cnt1, cnt2, bsum);
  k_scanb_both<<<1,1024,0,stream>>>(bsum, bbase, off1, off2);
  k_offsets_both<<<640,256,0,stream>>>(cnt1, cnt2, bbase, off1, off2);
  k_scatter_both<<<(E_LG_+E_G_)/256,256,0,stream>>>(eilg, eig, off1, cnt1, off2, cnt2,
                                                    srcs, eidp, eids);

  k_wprep<<<2048,256,0,stream>>>(srcs, eidp, dbas, ea_lg, W_nb, b_nb, W_eb, b_eb, w_sorted);

  // layer pipeline with ping-pong: raw hr[], transformed ht[]
  u16* hr[2] = {hr0, hr1};
  u16* ht[2] = {ht0, ht1};
  for (int l=0; l<4; l++){
    int pi = l & 1;          // input parity
    int po = pi ^ 1;         // output parity
    const u16* gin  = (l == 0) ? hr0 : ht[pi];
    const u16* hres = hr[pi];
    k_agg_gemm<<<E_G_/16,256,0,stream>>>(gin, hres, srcs, off1, w_sorted, t_vals, l,
        WTg + (size_t)l*128*128, b_gcn + l*128, gamma, beta,
        hr[po], ht[po], (l>0)?1:0, (l<3)?1:0);
  }
  // after 4 layers (l=3 writes parity 0): final raw in hr[0]

  k_pool_nodes<<<N_G_*32/256,256,0,stream>>>(hr[0], off2, eids, gamma, beta, node_emb);
  k_poolpred<<<B_,128,0,stream>>>(node_emb, bidx, W_pred, b_pred, flag, d_out);
}

// Round 16
// 514.799 us; speedup vs baseline: 1.1287x; 1.1287x over previous
//
#include <hip/hip_runtime.h>

typedef unsigned short u16;
typedef __attribute__((ext_vector_type(4))) float f32x4;
typedef __attribute__((ext_vector_type(8))) short short8;

#define N_G_   32768
#define E_G_   131072
#define E_LG_  262144
#define H_     128
#define B_     256
#define TASKS_ 10
#define KC_    96    // composed msg K (84 padded)
#define LDSTC_ 104   // LDS row stride (u16) for composed msg A tile
#define CPAD_  132   // padded f32 row stride for C epilogue tile
#define APAD_  136   // padded u16 row stride for fused agg->gemm A tile
#define SCAP_  256   // staged-src capacity per block
#define INVBN_ 0.9999950000374997f   // 1/sqrt(1+1e-5)
#define NCVT_  20
#define TOTAL_CANON_ 5352216

__device__ __forceinline__ float bf2f(u16 h){
  union { unsigned int u; float f; } v; v.u = ((unsigned int)h) << 16; return v.f;
}
__device__ __forceinline__ u16 f2bf(float f){
  union { float f; unsigned int u; } v; v.f = f;
  unsigned int u = v.u + 0x7fffu + ((v.u >> 16) & 1u);  // RNE
  return (u16)(u >> 16);
}

// ---- dtype detect
__global__ void k_detect(const unsigned int* __restrict__ x, int* __restrict__ flag){
  __shared__ int sm[256];
  unsigned int v = x[threadIdx.x];
  unsigned int e = (v >> 7) & 0xFFu;
  sm[threadIdx.x] = (e >= 110u && e <= 140u) ? 1 : 0;
  __syncthreads();
  for (int s=128;s>0;s>>=1){ if (threadIdx.x < s) sm[threadIdx.x] += sm[threadIdx.x+s]; __syncthreads(); }
  if (threadIdx.x == 0) flag[0] = (sm[0] > 128) ? 1 : 0;
}

struct CvtArgs { const void* src[NCVT_]; int start[NCVT_]; int count[NCVT_]; };

__global__ void k_cvt(CvtArgs a, int total, const int* __restrict__ flag, u16* __restrict__ dst){
  int i = blockIdx.x*256 + threadIdx.x;
  if (i >= total) return;
  int s = 0;
  #pragma unroll
  for (int j=1;j<NCVT_;j++) if (i >= a.start[j]) s = j;
  int off = i - a.start[s];
  if (off >= a.count[s]) { dst[i] = 0; return; }
  if (flag[0]) dst[i] = ((const u16*)a.src[s])[off];
  else         dst[i] = f2bf(((const float*)a.src[s])[off]);
}

// ---- pack: WTg [l][n][k]; composed WTc [n][96] = [Wenc@Wm1 | Wenc@Wm2 | Wm_ea | Wm_xlg]^T; bC
__global__ void k_pack(const u16* __restrict__ Wg, const u16* __restrict__ Wm,
                       const u16* __restrict__ Wenc, const u16* __restrict__ benc,
                       const u16* __restrict__ bmsg,
                       u16* __restrict__ WTg, u16* __restrict__ WTc, u16* __restrict__ bC){
  int idx = blockIdx.x*256 + threadIdx.x;
  if (idx < 4*128*128){
    int l = idx >> 14, n = (idx >> 7) & 127, k = idx & 127;
    WTg[idx] = Wg[((l<<7) + k)*128 + n];
    return;
  }
  int i2 = idx - 4*128*128;
  if (i2 < 128*KC_){
    int n = i2 / KC_, k = i2 % KC_;
    float v = 0.f;
    if (k < 32){
      for (int j=0;j<128;j++) v += bf2f(Wenc[k*128 + j]) * bf2f(Wm[j*128 + n]);
    } else if (k < 64){
      int kk = k - 32;
      for (int j=0;j<128;j++) v += bf2f(Wenc[kk*128 + j]) * bf2f(Wm[(128+j)*128 + n]);
    } else if (k < 80){
      v = bf2f(Wm[(256 + k - 64)*128 + n]);
    } else if (k < 84){
      v = bf2f(Wm[(272 + k - 80)*128 + n]);
    }
    WTc[n*KC_ + k] = f2bf(v);
    return;
  }
  int i3 = i2 - 128*KC_;
  if (i3 < 128){
    int n = i3;
    float v = bf2f(bmsg[n]);
    for (int j=0;j<128;j++)
      v += bf2f(benc[j]) * (bf2f(Wm[j*128 + n]) + bf2f(Wm[(128+j)*128 + n]));
    bC[n] = f2bf(v);
  }
}

// ---- msg GEMM (composed, K=96): h[e] = [x_src|x_dst|ea|xlg] @ Wc + bC
__global__ __launch_bounds__(256) void k_msg(const u16* __restrict__ xg, const u16* __restrict__ eag,
     const u16* __restrict__ xlg, const int* __restrict__ eig,
     const u16* __restrict__ WTc, const u16* __restrict__ bC, u16* __restrict__ h){
  __shared__ __align__(16) float Cs[64*CPAD_];   // 33792 B; staging tile As aliases (64*104 u16)
  u16* As = (u16*)Cs;
  int tid = threadIdx.x;
  int e0 = blockIdx.x * 64;
  {
    int i = tid >> 2;         // edge row 0..63
    int j = tid & 3;
    int e = e0 + i;
    u16* rowp = As + i*LDSTC_;
    if (j == 0){
      int s = eig[e];
      const u16* ps = xg + s*32;
      #pragma unroll
      for (int q=0;q<4;q++) *(short8*)(rowp + q*8) = *(const short8*)(ps + q*8);
    } else if (j == 1){
      int d = eig[E_G_ + e];
      const u16* pd = xg + d*32;
      #pragma unroll
      for (int q=0;q<4;q++) *(short8*)(rowp + 32 + q*8) = *(const short8*)(pd + q*8);
    } else if (j == 2){
      *(short8*)(rowp + 64) = *(const short8*)(eag + e*16);
      *(short8*)(rowp + 72) = *(const short8*)(eag + e*16 + 8);
    } else {
      *(ushort4*)(rowp + 80) = *(const ushort4*)(xlg + e*4);
      *(ushort4*)(rowp + 84) = (ushort4){0,0,0,0};
      *(short8*)(rowp + 88) = (short8){0,0,0,0,0,0,0,0};
    }
  }
  __syncthreads();
  int wave = tid >> 6, lane = tid & 63, quad = lane >> 4, l16 = lane & 15;
  int arow = wave*16 + l16;
  f32x4 acc[8];
  #pragma unroll
  for (int ct=0;ct<8;ct++) acc[ct] = (f32x4){0.f,0.f,0.f,0.f};
  #pragma unroll
  for (int ks=0; ks<KC_; ks+=32){
    short8 af = *(const short8*)(As + arow*LDSTC_ + ks + quad*8);
    #pragma unroll
    for (int ct=0;ct<8;ct++){
      short8 bfr = *(const short8*)(WTc + (ct*16 + l16)*KC_ + ks + quad*8);
      acc[ct] = __builtin_amdgcn_mfma_f32_16x16x32_bf16(af, bfr, acc[ct], 0,0,0);
    }
  }
  __syncthreads();    // done with As
  {
    int lrow = wave*16 + quad*4;
    #pragma unroll
    for (int ct=0;ct<8;ct++){
      int col = ct*16 + l16;
      #pragma unroll
      for (int i=0;i<4;i++) Cs[(lrow+i)*CPAD_ + col] = acc[ct][i];
    }
  }
  __syncthreads();
  #pragma unroll
  for (int p=0;p<4;p++){
    int s = p*256 + tid;
    int lrow = s >> 4, c0 = (s & 15) * 8;
    const float* cp = Cs + lrow*CPAD_ + c0;
    short8 bs = *(const short8*)(bC + c0);
    short8 ov;
    #pragma unroll
    for (int k=0;k<8;k++) ov[k] = (short)f2bf(cp[k] + bf2f((u16)bs[k]));
    *(short8*)(h + (size_t)(e0 + lrow)*128 + c0) = ov;
  }
}

// ---- FUSED: softmax-agg (16 dsts, staged srcs, prefetched) -> LDS -> MFMA -> epilogue w/ h2
__global__ __launch_bounds__(256) void k_agg_gemm(
    const u16* __restrict__ gin,      // gather input (pre-transformed for l>0)
    const u16* __restrict__ hres,     // residual input (raw)
    const int* __restrict__ srcs, const int* __restrict__ off,
    const u16* __restrict__ w, const u16* __restrict__ tvals, int layer,
    const u16* __restrict__ WT, const u16* __restrict__ bg,
    const u16* __restrict__ gamma, const u16* __restrict__ beta,
    u16* __restrict__ hout, u16* __restrict__ h2out, int residual, int write_h2){
  __shared__ __align__(16) float Cs[16*CPAD_];      // 8448 B; aliased as u16 As (stride APAD_)
  __shared__ int srcs_s[SCAP_];
  u16* As = (u16*)Cs;
  int tid = threadIdx.x;
  int e0 = blockIdx.x*16;

  // ---- stage block's src list (breaks the dependent-load chain)
  int kbB = off[e0], keB = off[e0+16];
  int cnt = keB - kbB;
  for (int i = tid; i < cnt && i < SCAP_; i += 256) srcs_s[i] = srcs[kbB + i];
  __syncthreads();

  // ---- phase A: per-dst serial softmax-agg with k+1 prefetch
  {
    int r = tid >> 4;
    int c0 = (tid & 15) * 8;
    int g = e0 + r;
    float t = bf2f(tvals[layer]);
    float den[8]={0.f,0.f,0.f,0.f,0.f,0.f,0.f,0.f};
    float num[8]={0.f,0.f,0.f,0.f,0.f,0.f,0.f,0.f};
    int kb = off[g], ke = off[g+1];
    short8 xu, wu;
    if (kb < ke){
      int i0 = kb - kbB;
      int s0 = (i0 < SCAP_) ? srcs_s[i0] : srcs[kb];
      xu = *(const short8*)(gin + (size_t)s0*128 + c0);
      wu = *(const short8*)(w + (size_t)kb*128 + c0);
    }
    for (int k = kb; k < ke; k++){
      short8 xn, wn;
      if (k+1 < ke){
        int i1 = k+1 - kbB;
        int s1 = (i1 < SCAP_) ? srcs_s[i1] : srcs[k+1];
        xn = *(const short8*)(gin + (size_t)s1*128 + c0);
        wn = *(const short8*)(w + (size_t)(k+1)*128 + c0);
      }
      #pragma unroll
      for (int j=0;j<8;j++){
        float m  = fmaxf(bf2f((u16)xu[j])*bf2f((u16)wu[j]), 0.f);
        float e1 = __expf(m*t);
        den[j] += e1;
        num[j] = fmaf(e1, m, num[j]);
      }
      xu = xn; wu = wn;
    }
    short8 xdu = *(const short8*)(gin + (size_t)g*128 + c0);
    short8 ov;
    #pragma unroll
    for (int j=0;j<8;j++)
      ov[j] = (short)f2bf(bf2f((u16)xdu[j]) + (den[j] > 0.f ? num[j]/den[j] : 0.f));
    *(short8*)(As + r*APAD_ + c0) = ov;
  }
  __syncthreads();

  // ---- phase B: 4 waves; wave handles 2 col-tiles of the 16x128 output
  int wave = tid >> 6, lane = tid & 63, quad = lane >> 4, l16 = lane & 15;
  f32x4 acc[2];
  acc[0] = (f32x4){0.f,0.f,0.f,0.f};
  acc[1] = (f32x4){0.f,0.f,0.f,0.f};
  #pragma unroll
  for (int ks=0;ks<128;ks+=32){
    short8 af = *(const short8*)(As + l16*APAD_ + ks + quad*8);
    #pragma unroll
    for (int c2=0;c2<2;c2++){
      int ct = wave*2 + c2;
      short8 bfr = *(const short8*)(WT + (ct*16 + l16)*128 + ks + quad*8);
      acc[c2] = __builtin_amdgcn_mfma_f32_16x16x32_bf16(af, bfr, acc[c2], 0,0,0);
    }
  }
  __syncthreads();      // done reading As; Cs aliases it
  {
    int lrow = quad*4;
    #pragma unroll
    for (int c2=0;c2<2;c2++){
      int col = (wave*2 + c2)*16 + l16;
      #pragma unroll
      for (int i=0;i<4;i++) Cs[(lrow+i)*CPAD_ + col] = acc[c2][i];
    }
  }
  __syncthreads();

  // ---- epilogue: hout = C + b (+ res); h2out = relu(bn(hout)) if requested
  {
    int lrow = tid >> 4, ce = (tid & 15) * 8;
    const float* cp = Cs + lrow*CPAD_ + ce;
    size_t goff = (size_t)(e0 + lrow)*128 + ce;
    short8 bs = *(const short8*)(bg + ce);
    float v[8];
    #pragma unroll
    for (int k=0;k<8;k++) v[k] = cp[k] + bf2f((u16)bs[k]);
    if (residual){
      short8 hs = *(const short8*)(hres + goff);
      #pragma unroll
      for (int k=0;k<8;k++) v[k] += bf2f((u16)hs[k]);
    }
    short8 ov;
    #pragma unroll
    for (int k=0;k<8;k++) ov[k] = (short)f2bf(v[k]);
    *(short8*)(hout + goff) = ov;
    if (write_h2){
      short8 gs = *(const short8*)(gamma + layer*128 + ce);
      short8 es = *(const short8*)(beta  + layer*128 + ce);
      short8 o2;
      #pragma unroll
      for (int k=0;k<8;k++)
        o2[k] = (short)f2bf(fmaxf(fmaf(v[k], bf2f((u16)gs[k])*INVBN_, bf2f((u16)es[k])), 0.f));
      *(short8*)(h2out + goff) = o2;
    }
  }
}

// ---- merged CSR build: counts for both graphs in one dispatch
__global__ void k_count_both(const int* __restrict__ eilg_dst, const int* __restrict__ eig_dst,
                             int* __restrict__ cnt1, int* __restrict__ cnt2){
  int i = blockIdx.x*256 + threadIdx.x;
  if (i < E_LG_) atomicAdd(&cnt1[eilg_dst[i]], 1);
  else {
    int j = i - E_LG_;
    if (j < E_G_) atomicAdd(&cnt2[eig_dst[j]], 1);
  }
}
__global__ void k_bsum_both(const int* __restrict__ cnt1, const int* __restrict__ cnt2,
                            int* __restrict__ bsum){
  __shared__ int sm[256];
  int b = blockIdx.x;
  int v;
  if (b < 512) v = cnt1[b*256 + threadIdx.x];
  else         v = cnt2[(b-512)*256 + threadIdx.x];
  sm[threadIdx.x] = v;
  __syncthreads();
  for (int s=128;s>0;s>>=1){ if (threadIdx.x < s) sm[threadIdx.x] += sm[threadIdx.x+s]; __syncthreads(); }
  if (threadIdx.x==0) bsum[b] = sm[0];
}
__global__ void k_scanb_both(const int* __restrict__ bsum, int* __restrict__ bbase,
                             int* __restrict__ off1, int* __restrict__ off2){
  __shared__ int sm[1024];
  int t = threadIdx.x;
  {
    int v = (t < 512) ? bsum[t] : 0;
    sm[t] = v; __syncthreads();
    for (int d=1; d<1024; d<<=1){
      int u = (t>=d) ? sm[t-d] : 0;
      __syncthreads();
      sm[t] += u;
      __syncthreads();
    }
    if (t < 512) bbase[t] = sm[t] - v;
    if (t == 511) off1[E_G_] = sm[511];
  }
  __syncthreads();
  {
    int v = (t < 128) ? bsum[512 + t] : 0;
    sm[t] = v; __syncthreads();
    for (int d=1; d<1024; d<<=1){
      int u = (t>=d) ? sm[t-d] : 0;
      __syncthreads();
      sm[t] += u;
      __syncthreads();
    }
    if (t < 128) bbase[512 + t] = sm[t] - v;
    if (t == 127) off2[N_G_] = sm[127];
  }
}
// 640 blocks; also zeroes cnt in place (becomes scatter cursor)
__global__ void k_offsets_both(int* __restrict__ cnt1, int* __restrict__ cnt2,
                               const int* __restrict__ bbase,
                               int* __restrict__ off1, int* __restrict__ off2){
  __shared__ int sm[256];
  int b = blockIdx.x;
  int t = threadIdx.x;
  int* cnt; int* off; int i;
  if (b < 512){ cnt = cnt1; off = off1; i = b*256 + t; }
  else        { cnt = cnt2; off = off2; i = (b-512)*256 + t; }
  int v = cnt[i];
  cnt[i] = 0;
  sm[t] = v; __syncthreads();
  for (int d=1; d<256; d<<=1){
    int u = (t>=d) ? sm[t-d] : 0;
    __syncthreads();
    sm[t] += u;
    __syncthreads();
  }
  off[i] = bbase[b] + sm[t] - v;
}
__global__ void k_scatter_both(const int* __restrict__ eilg, const int* __restrict__ eig,
                               const int* __restrict__ off1, int* __restrict__ cnt1,
                               const int* __restrict__ off2, int* __restrict__ cnt2,
                               int* __restrict__ srcs, int* __restrict__ eidp,
                               int* __restrict__ eids){
  int i = blockIdx.x*256 + threadIdx.x;
  if (i < E_LG_){
    int s = eilg[i], d = eilg[E_LG_ + i];
    int p = off1[d] + atomicAdd(&cnt1[d], 1);
    srcs[p] = s;
    eidp[p] = i;
  } else {
    int e = i - E_LG_;
    if (e < E_G_){
      int d = eig[E_G_ + e];
      int p = off2[d] + atomicAdd(&cnt2[d], 1);
      eids[p] = e;
    }
  }
}

// ---- precompute w_sorted (bf16; grid-stride persistent, 16 lanes x 8 ch)
__global__ __launch_bounds__(256) void k_wprep(const int* __restrict__ srcs, const int* __restrict__ eidp,
    const u16* __restrict__ dbas, const u16* __restrict__ ealg,
    const u16* __restrict__ Wnb, const u16* __restrict__ bnb,
    const u16* __restrict__ Web, const u16* __restrict__ beb,
    u16* __restrict__ w){
  int c0 = (threadIdx.x & 15) * 8;
  float wnb[4][8], web[4][8], vbn[8], vbe[8];
  #pragma unroll
  for (int i=0;i<4;i++){
    short8 a = *(const short8*)(Wnb + i*128 + c0);
    short8 b = *(const short8*)(Web + i*128 + c0);
    #pragma unroll
    for (int j=0;j<8;j++){ wnb[i][j]=bf2f((u16)a[j]); web[i][j]=bf2f((u16)b[j]); }
  }
  {
    short8 a = *(const short8*)(bnb + c0);
    short8 b = *(const short8*)(beb + c0);
    #pragma unroll
    for (int j=0;j<8;j++){ vbn[j]=bf2f((u16)a[j]); vbe[j]=bf2f((u16)b[j]); }
  }
  int g0 = blockIdx.x*16 + (threadIdx.x >> 4);
  int gs = gridDim.x*16;
  for (int p = g0; p < E_LG_; p += gs){
    int sidx = srcs[p];
    int eidx = eidp[p];
    ushort4 du = *(const ushort4*)(dbas + sidx*4);
    ushort4 eu = *(const ushort4*)(ealg + eidx*4);
    float db[4] = {bf2f(du.x), bf2f(du.y), bf2f(du.z), bf2f(du.w)};
    float ev[4] = {bf2f(eu.x), bf2f(eu.y), bf2f(eu.z), bf2f(eu.w)};
    short8 ov;
    #pragma unroll
    for (int j=0;j<8;j++){
      float nbv = vbn[j] + db[0]*wnb[0][j] + db[1]*wnb[1][j] + db[2]*wnb[2][j] + db[3]*wnb[3][j];
      float ebv = vbe[j] + ev[0]*web[0][j] + ev[1]*web[1][j] + ev[2]*web[2][j] + ev[3]*web[3][j];
      ov[j] = (short)f2bf(nbv * ebv);
    }
    *(short8*)(w + (size_t)p*128 + c0) = ov;
  }
}

// ---- stage 1 pooling: final bn + per-node edge-sum -> node_emb (bf16)
__global__ __launch_bounds__(256) void k_pool_nodes(const u16* __restrict__ h, const int* __restrict__ off2,
    const int* __restrict__ eids,
    const u16* __restrict__ gamma, const u16* __restrict__ beta,
    u16* __restrict__ node_emb){
  int tid = blockIdx.x*256 + threadIdx.x;
  int n = tid >> 5;
  int c0 = (tid & 31)*4;
  ushort4 ga = *(const ushort4*)(gamma + 3*128 + c0);
  ushort4 be = *(const ushort4*)(beta + 3*128 + c0);
  float gg[4] = {bf2f(ga.x)*INVBN_, bf2f(ga.y)*INVBN_, bf2f(ga.z)*INVBN_, bf2f(ga.w)*INVBN_};
  float bt[4] = {bf2f(be.x), bf2f(be.y), bf2f(be.z), bf2f(be.w)};
  float s[4] = {0.f,0.f,0.f,0.f};
  int kb = off2[n], ke = off2[n+1];
  for (int k=kb; k<ke; k++){
    int e = eids[k];
    ushort4 xu = *(const ushort4*)(h + (size_t)e*128 + c0);
    float xs[4] = {bf2f(xu.x), bf2f(xu.y), bf2f(xu.z), bf2f(xu.w)};
    #pragma unroll
    for (int j=0;j<4;j++) s[j] += fmaf(xs[j], gg[j], bt[j]);
  }
  ushort4 ov;
  ov.x = f2bf(s[0]); ov.y = f2bf(s[1]); ov.z = f2bf(s[2]); ov.w = f2bf(s[3]);
  *(ushort4*)(node_emb + (size_t)n*128 + c0) = ov;
}

// ---- stage 2: per-batch mean + fused prediction GEMV
__global__ __launch_bounds__(128) void k_poolpred(const u16* __restrict__ node_emb,
    const int* __restrict__ bidx,
    const u16* __restrict__ Wp, const u16* __restrict__ bp,
    const int* __restrict__ flag, void* __restrict__ out){
  int b = blockIdx.x;
  int t = threadIdx.x;
  int lo = 0, hi_s = N_G_;
  { int l = 0, r = N_G_;
    while (l < r){ int m = (l+r)>>1; if (bidx[m] < b) l = m+1; else r = m; }
    lo = l;
    l = lo; r = N_G_;
    while (l < r){ int m = (l+r)>>1; if (bidx[m] < b+1) l = m+1; else r = m; }
    hi_s = l;
  }
  float s = 0.f;
  for (int n=lo; n<hi_s; n++) s += bf2f(node_emb[(size_t)n*128 + t]);
  __shared__ float sm[128];
  sm[t] = s;
  __syncthreads();
  if (t < TASKS_){
    float inv = 1.0f / fmaxf((float)(hi_s - lo), 1.0f);
    float acc = bf2f(bp[t]);
    #pragma unroll 4
    for (int c=0;c<128;c++) acc += sm[c]*inv * bf2f(Wp[c*TASKS_ + t]);
    if (flag[0]) ((u16*)out)[b*TASKS_ + t] = f2bf(acc);
    else         ((float*)out)[b*TASKS_ + t] = acc;
  }
}

extern "C" void kernel_launch(void* const* d_in, const int* in_sizes, int n_in,
                              void* d_out, int out_size, void* d_ws, size_t ws_size,
                              hipStream_t stream){
  const int* eig  = (const int*)d_in[5];
  const int* eilg = (const int*)d_in[6];
  const int* bidx = (const int*)d_in[7];

  char* ws = (char*)d_ws; size_t o = 0;
  auto carve = [&](size_t b)->char*{ char* p = ws + o; o += (b + 255) & ~(size_t)255; return p; };
  int*  flag  = (int*) carve(256);
  u16*  canon = (u16*) carve((size_t)TOTAL_CANON_*2);
  u16*  hr0   = (u16*) carve((size_t)E_G_*H_*2);   // raw ping
  u16*  hr1   = (u16*) carve((size_t)E_G_*H_*2);   // raw pong
  u16*  ht0   = (u16*) carve((size_t)E_G_*H_*2);   // transformed ping
  u16*  ht1   = (u16*) carve((size_t)E_G_*H_*2);   // transformed pong
  u16*  WTg   = (u16*) carve((size_t)4*128*128*2);
  u16*  WTc   = (u16*) carve((size_t)128*KC_*2);
  u16*  bC    = (u16*) carve((size_t)128*2);
  int*  cntB  = (int*) carve((size_t)(E_G_+N_G_)*4);   // cnt1 | cnt2 contiguous
  int*  cnt1  = cntB;
  int*  cnt2  = cntB + E_G_;
  int*  off1  = (int*) carve((size_t)(E_G_+1)*4);
  int*  off2  = (int*) carve((size_t)(N_G_+1)*4);
  int*  srcs  = (int*) carve((size_t)E_LG_*4);
  int*  eidp  = (int*) carve((size_t)E_LG_*4);
  int*  eids  = (int*) carve((size_t)E_G_*4);
  int*  bsum  = (int*) carve(1024*4);
  int*  bbase = (int*) carve(1024*4);
  u16*  node_emb = (u16*)carve((size_t)N_G_*H_*2);
  u16*  w_sorted = (u16*)carve((size_t)E_LG_*H_*2);
  (void)in_sizes; (void)n_in; (void)out_size; (void)ws_size;

  static const int di[NCVT_] = {0,1,2,3,4, 8,9,10,11,12,13,14,15,16,17,18,19,20,21,22};
  static const int st[NCVT_] = {0,1048576,3145728,3670016,4194304,
                                5242880,5246976,5247104,5282432,5282560,
                                5283072,5283200,5283712,5283840,5349376,
                                5349888,5349896,5350408,5350920,5352200};
  static const int cn[NCVT_] = {1048576,2097152,524288,524288,1048576,
                                4096,128,35328,128,512,
                                128,512,128,65536,512,
                                4,512,512,1280,10};
  CvtArgs ca;
  for (int i=0;i<NCVT_;i++){ ca.src[i]=d_in[di[i]]; ca.start[i]=st[i]; ca.count[i]=cn[i]; }

  const u16* x_g   = canon + st[0];
  const u16* ea_g  = canon + st[1];
  const u16* x_lg  = canon + st[2];
  const u16* dbas  = canon + st[3];
  const u16* ea_lg = canon + st[4];
  const u16* W_enc = canon + st[5];
  const u16* b_enc = canon + st[6];
  const u16* W_msg = canon + st[7];
  const u16* b_msg = canon + st[8];
  const u16* W_nb  = canon + st[9];
  const u16* b_nb  = canon + st[10];
  const u16* W_eb  = canon + st[11];
  const u16* b_eb  = canon + st[12];
  const u16* W_gcn = canon + st[13];
  const u16* b_gcn = canon + st[14];
  const u16* t_vals= canon + st[15];
  const u16* gamma = canon + st[16];
  const u16* beta  = canon + st[17];
  const u16* W_pred= canon + st[18];
  const u16* b_pred= canon + st[19];

  k_detect<<<1,256,0,stream>>>((const unsigned int*)d_in[0], flag);
  k_cvt<<<(TOTAL_CANON_+255)/256,256,0,stream>>>(ca, TOTAL_CANON_, flag, canon);

  k_pack<<<(4*128*128 + 128*KC_ + 128 + 255)/256,256,0,stream>>>(
      W_gcn, W_msg, W_enc, b_enc, b_msg, WTg, WTc, bC);
  k_msg<<<E_G_/64,256,0,stream>>>(x_g, ea_g, x_lg, eig, WTc, bC, hr0);

  // merged CSR build (line-graph dst + graph dst)
  hipMemsetAsync(cntB, 0, (size_t)(E_G_+N_G_)*4, stream);
  k_count_both<<<(E_LG_+E_G_)/256,256,0,stream>>>(eilg + E_LG_, eig + E_G_, cnt1, cnt2);
  k_bsum_both<<<640,256,0,stream>>>(cnt1, cnt2, bsum);
  k_scanb_both<<<1,1024,0,stream>>>(bsum, bbase, off1, off2);
  k_offsets_both<<<640,256,0,stream>>>(cnt1, cnt2, bbase, off1, off2);
  k_scatter_both<<<(E_LG_+E_G_)/256,256,0,stream>>>(eilg, eig, off1, cnt1, off2, cnt2,
                                                    srcs, eidp, eids);

  k_wprep<<<2048,256,0,stream>>>(srcs, eidp, dbas, ea_lg, W_nb, b_nb, W_eb, b_eb, w_sorted);

  // layer pipeline with ping-pong: raw hr[], transformed ht[]
  u16* hr[2] = {hr0, hr1};
  u16* ht[2] = {ht0, ht1};
  for (int l=0; l<4; l++){
    int pi = l & 1;          // input parity
    int po = pi ^ 1;         // output parity
    const u16* gin  = (l == 0) ? hr0 : ht[pi];
    const u16* hres = hr[pi];
    k_agg_gemm<<<E_G_/16,256,0,stream>>>(gin, hres, srcs, off1, w_sorted, t_vals, l,
        WTg + (size_t)l*128*128, b_gcn + l*128, gamma, beta,
        hr[po], ht[po], (l>0)?1:0, (l<3)?1:0);
  }
  // after 4 layers (l=3 writes parity 0): final raw in hr[0]

  k_pool_nodes<<<N_G_*32/256,256,0,stream>>>(hr[0], off2, eids, gamma, beta, node_emb);
  k_poolpred<<<B_,128,0,stream>>>(node_emb, bidx, W_pred, b_pred, flag, d_out);
}